// Round 9
// baseline (584.845 us; speedup 1.0000x reference)
//
#include <hip/hip_runtime.h>

typedef short v8s __attribute__((ext_vector_type(8)));
typedef float v4f __attribute__((ext_vector_type(4)));

#define Wh   1024
#define HWh  (1024 * 512)
#define Wlr  512
#define HWlr (512 * 256)

#define THREADS 1024
#define NBLK    512       // 2 blocks/CU; 512 * 4 iters * 16 waves * 16 px = 524288
#define ITERS   4

// LDS holds ONLY weight A-fragments: W0:32, W1:16, W2:4, W3:1 = 53 frags
#define WFRAG_SHORTS (53 * 512)   // 54272 B/block -> 2 blocks = 108.5 KB <= 160 KB

__device__ __forceinline__ unsigned short f2bf(float f) {
    union { float f; unsigned u; } v; v.f = f;
    unsigned r = v.u + 0x7FFFu + ((v.u >> 16) & 1u);  // RNE (cold paths only)
    return (unsigned short)(r >> 16);
}
// hot-path pack: round-half-up bias + v_perm grabbing the two high halves (3 VALU)
__device__ __forceinline__ unsigned pk2(float a, float b) {
    union { float f; unsigned u; } ua, ub;
    ua.f = a; ub.f = b;
    return __builtin_amdgcn_perm(ub.u + 0x8000u, ua.u + 0x8000u, 0x07060302u);
}
__device__ __forceinline__ float leaky(float x) { return fmaxf(x, 0.01f * x); }

// C-layout -> B-layout transpose for one 32-ch k-slice, all in registers.
// pdA = packed dwords of mt = 2*ksl (s=0,1), pdB = mt = 2*ksl+1.
// Target lane (px=p, q) dword d holds ch pair {32ks+8q+2d, +1}; source lane
// qsrc = (2q+(d>>1))&3 (*16+p), source reg s = d&1, mt-select by (q>>1).
__device__ __forceinline__ v8s xpose(unsigned a0, unsigned a1, unsigned b0, unsigned b1,
                                     int adr0, int adr1, bool low) {
    unsigned r0a = __builtin_amdgcn_ds_bpermute(adr0, a0);
    unsigned r0b = __builtin_amdgcn_ds_bpermute(adr0, b0);
    unsigned r1a = __builtin_amdgcn_ds_bpermute(adr0, a1);
    unsigned r1b = __builtin_amdgcn_ds_bpermute(adr0, b1);
    unsigned r2a = __builtin_amdgcn_ds_bpermute(adr1, a0);
    unsigned r2b = __builtin_amdgcn_ds_bpermute(adr1, b0);
    unsigned r3a = __builtin_amdgcn_ds_bpermute(adr1, a1);
    unsigned r3b = __builtin_amdgcn_ds_bpermute(adr1, b1);
    union { uint4 u; v8s s; } c;
    c.u.x = low ? r0a : r0b;
    c.u.y = low ? r1a : r1b;
    c.u.z = low ? r2a : r2b;
    c.u.w = low ? r3a : r3b;
    return c.s;
}

__global__ __launch_bounds__(THREADS, 8)
void cmfsm_kernel(const float* __restrict__ lr, const float* __restrict__ hr,
                  const float* __restrict__ w0g, const float* __restrict__ w1g,
                  const float* __restrict__ w2g, const float* __restrict__ w3g,
                  const float* __restrict__ w4g, const float* __restrict__ w5g,
                  const float* __restrict__ t0g, const float* __restrict__ t1g,
                  const float* __restrict__ t2g, const float* __restrict__ fwg,
                  float* __restrict__ out)
{
    __shared__ unsigned short wfrag[WFRAG_SHORTS];

    const int tid  = threadIdx.x;
    const int lane = tid & 63;
    const int wv   = tid >> 6;
    const int p    = lane & 15;   // MFMA n (pixel)
    const int q    = lane >> 4;   // MFMA k-quad

    // ---- stage weights as lane-contiguous A-fragments ----
    for (int e = tid; e < 32 * 64; e += THREADS) {
        int f = e >> 6, l = e & 63;
        int mt = f >> 2, ks = f & 3, pp = l & 15, qq = l >> 4;
        const float* src = w0g + (mt * 16 + pp) * 128 + ks * 32 + qq * 8;
        unsigned short* dst = wfrag + f * 512 + l * 8;
#pragma unroll
        for (int j = 0; j < 8; ++j) dst[j] = f2bf(src[j]);
    }
    {   // W1: frags 32..47 (exactly 1024 lanes of work)
        int f = tid >> 6, l = tid & 63;
        int mt = f >> 2, ks = f & 3, pp = l & 15, qq = l >> 4;
        const float* src = w1g + (mt * 16 + pp) * 128 + ks * 32 + qq * 8;
        unsigned short* dst = wfrag + (32 + f) * 512 + l * 8;
#pragma unroll
        for (int j = 0; j < 8; ++j) dst[j] = f2bf(src[j]);
    }
    if (tid < 4 * 64) {
        int f = tid >> 6, l = tid & 63;
        int mt = f >> 1, ks = f & 1, pp = l & 15, qq = l >> 4;
        const float* src = w2g + (mt * 16 + pp) * 64 + ks * 32 + qq * 8;
        unsigned short* dst = wfrag + (48 + f) * 512 + l * 8;
#pragma unroll
        for (int j = 0; j < 8; ++j) dst[j] = f2bf(src[j]);
    }
    if (tid < 64) {
        int l = tid, pp = l & 15, qq = l >> 4;
        const float* src = w3g + pp * 32 + qq * 8;
        unsigned short* dst = wfrag + 52 * 512 + l * 8;
#pragma unroll
        for (int j = 0; j < 8; ++j) dst[j] = f2bf(src[j]);
    }

    // ---- fused layers 4+5: w45[r] = sum_j w5[j]*w4[j][4q+r] ----
    float w45[4];
#pragma unroll
    for (int r = 0; r < 4; ++r) {
        float s = 0.f;
#pragma unroll
        for (int j = 0; j < 8; ++j) s += w5g[j] * w4g[j * 16 + q * 4 + r];
        w45[r] = s;
    }

    // ---- weights2: 4 parity values ----
    float w2tab[4];
#pragma unroll
    for (int yp = 0; yp < 2; ++yp)
#pragma unroll
        for (int xp = 0; xp < 2; ++xp) {
            float i0 = xp ? 1.f : -1.f;
            float i1 = yp ? 1.f : -1.f;
            float i2 = 1.41421356237309505f;
            float h0[3], h1[2];
            for (int o = 0; o < 3; ++o)
                h0[o] = leaky(t0g[o*3+0]*i0 + t0g[o*3+1]*i1 + t0g[o*3+2]*i2);
            for (int o = 0; o < 2; ++o)
                h1[o] = leaky(t1g[o*3+0]*h0[0] + t1g[o*3+1]*h0[1] + t1g[o*3+2]*h0[2]);
            w2tab[yp*2+xp] = t2g[0]*h1[0] + t2g[1]*h1[1];
        }
    const float fa = fabsf(fwg[0]);
    const float fb = fabsf(fwg[1]);

    // bpermute byte-addresses (lane constants): qsrc = (2q + dhi)&3, lane = qsrc*16+p
    const int adr0 = ((((2 * q) + 0) & 3) * 16 + p) << 2;
    const int adr1 = ((((2 * q) + 1) & 3) * 16 + p) << 2;
    const bool low = (q < 2);

    __syncthreads();   // wfrag ready
    const v4f z4 = (v4f){0.f, 0.f, 0.f, 0.f};

#pragma unroll 1
    for (int it = 0; it < ITERS; ++it) {
        const int gbase = (blockIdx.x * ITERS + it) * 256 + wv * 16;
        const int y     = gbase >> 10;
        const int xg    = (gbase & 1023) + p;

        // ---- build rep B-fragments directly in registers ----
        // lane (p,q) needs input channels 8q..8q+7 at its own pixel
        float h[8], l[8];
        {
            const float* hb = hr + (size_t)y * Wh + xg;
            const float* lb = lr + (size_t)(y >> 1) * Wlr + (xg >> 1);
#pragma unroll
            for (int j = 0; j < 8; ++j) {
                h[j] = hb[(size_t)(8 * q + j) * HWh];
                l[j] = lb[(size_t)(8 * q + j) * HWlr];
            }
        }
        v8s bfr[4];
        {
            unsigned* b0 = (unsigned*)&bfr[0];
            unsigned* b1 = (unsigned*)&bfr[1];
            unsigned* b2 = (unsigned*)&bfr[2];
            unsigned* b3 = (unsigned*)&bfr[3];
#pragma unroll
            for (int jj = 0; jj < 4; ++jj) {
                float l0 = l[2*jj], l1 = l[2*jj+1];
                float h0 = h[2*jj], h1 = h[2*jj+1];
                b0[jj] = pk2(l0, l1);                 // lr_up
                b1[jj] = pk2(h0, h1);                 // hr
                b2[jj] = pk2(l0 * h0, l1 * h1);       // product
                float d0 = l0 - h0, d1 = l1 - h1;
                b3[jj] = pk2(d0 * d0, d1 * d1);       // squared diff
            }
        }

        // ---- layer 0: 128 -> 128 in two mt-halves; emit next B-frags via bpermute ----
        v8s nb[4];
#pragma unroll
        for (int mh = 0; mh < 2; ++mh) {
            v4f acc[4];
#pragma unroll
            for (int ks = 0; ks < 4; ++ks)
#pragma unroll
                for (int mi = 0; mi < 4; ++mi) {
                    v8s a = *(const v8s*)(wfrag + ((mh * 4 + mi) * 4 + ks) * 512 + lane * 8);
                    acc[mi] = __builtin_amdgcn_mfma_f32_16x16x32_bf16(
                        a, bfr[ks], ks == 0 ? z4 : acc[mi], 0, 0, 0);
                }
            unsigned pd[4][2];
#pragma unroll
            for (int mi = 0; mi < 4; ++mi) {
                pd[mi][0] = pk2(leaky(acc[mi][0]), leaky(acc[mi][1]));
                pd[mi][1] = pk2(leaky(acc[mi][2]), leaky(acc[mi][3]));
            }
            nb[2*mh + 0] = xpose(pd[0][0], pd[0][1], pd[1][0], pd[1][1], adr0, adr1, low);
            nb[2*mh + 1] = xpose(pd[2][0], pd[2][1], pd[3][0], pd[3][1], adr0, adr1, low);
        }

        // ---- layer 1: 128 -> 64 ----
        v8s b2f[2];
        {
            v4f acc[4];
#pragma unroll
            for (int ks = 0; ks < 4; ++ks)
#pragma unroll
                for (int mt = 0; mt < 4; ++mt) {
                    v8s a = *(const v8s*)(wfrag + (32 + mt * 4 + ks) * 512 + lane * 8);
                    acc[mt] = __builtin_amdgcn_mfma_f32_16x16x32_bf16(
                        a, nb[ks], ks == 0 ? z4 : acc[mt], 0, 0, 0);
                }
            unsigned pd[4][2];
#pragma unroll
            for (int mt = 0; mt < 4; ++mt) {
                pd[mt][0] = pk2(leaky(acc[mt][0]), leaky(acc[mt][1]));
                pd[mt][1] = pk2(leaky(acc[mt][2]), leaky(acc[mt][3]));
            }
            b2f[0] = xpose(pd[0][0], pd[0][1], pd[1][0], pd[1][1], adr0, adr1, low);
            b2f[1] = xpose(pd[2][0], pd[2][1], pd[3][0], pd[3][1], adr0, adr1, low);
        }

        // ---- layer 2: 64 -> 32 ----
        v8s b3f;
        {
            v4f acc[2];
#pragma unroll
            for (int ks = 0; ks < 2; ++ks)
#pragma unroll
                for (int mt = 0; mt < 2; ++mt) {
                    v8s a = *(const v8s*)(wfrag + (48 + mt * 2 + ks) * 512 + lane * 8);
                    acc[mt] = __builtin_amdgcn_mfma_f32_16x16x32_bf16(
                        a, b2f[ks], ks == 0 ? z4 : acc[mt], 0, 0, 0);
                }
            unsigned pd[2][2];
#pragma unroll
            for (int mt = 0; mt < 2; ++mt) {
                pd[mt][0] = pk2(leaky(acc[mt][0]), leaky(acc[mt][1]));
                pd[mt][1] = pk2(leaky(acc[mt][2]), leaky(acc[mt][3]));
            }
            b3f = xpose(pd[0][0], pd[0][1], pd[1][0], pd[1][1], adr0, adr1, low);
        }

        // ---- layer 3: 32 -> 16, fused 16->8->1, fuse with weights2 ----
        {
            v8s a = *(const v8s*)(wfrag + 52 * 512 + lane * 8);
            v4f acc3 = __builtin_amdgcn_mfma_f32_16x16x32_bf16(a, b3f, z4, 0, 0, 0);

            float part = 0.f;
#pragma unroll
            for (int r = 0; r < 4; ++r) part += w45[r] * leaky(acc3[r]);
            part += __shfl_xor(part, 16, 64);
            part += __shfl_xor(part, 32, 64);

            if (q == 0) {
                out[y * Wh + xg] = fa * part + fb * w2tab[((y & 1) << 1) | (xg & 1)];
            }
        }
    }
}

extern "C" void kernel_launch(void* const* d_in, const int* in_sizes, int n_in,
                              void* d_out, int out_size, void* d_ws, size_t ws_size,
                              hipStream_t stream) {
    const float* lr  = (const float*)d_in[0];
    const float* hr  = (const float*)d_in[1];
    const float* w0g = (const float*)d_in[2];
    const float* w1g = (const float*)d_in[3];
    const float* w2g = (const float*)d_in[4];
    const float* w3g = (const float*)d_in[5];
    const float* w4g = (const float*)d_in[6];
    const float* w5g = (const float*)d_in[7];
    const float* t0g = (const float*)d_in[8];
    const float* t1g = (const float*)d_in[9];
    const float* t2g = (const float*)d_in[10];
    const float* fwg = (const float*)d_in[11];
    float* out = (float*)d_out;

    hipLaunchKernelGGL(cmfsm_kernel, dim3(NBLK), dim3(THREADS), 0, stream,
                       lr, hr, w0g, w1g, w2g, w3g, w4g, w5g, t0g, t1g, t2g, fwg, out);
}

// Round 10
// 154.162 us; speedup vs baseline: 3.7937x; 3.7937x over previous
//
#include <hip/hip_runtime.h>

typedef short v8s __attribute__((ext_vector_type(8)));
typedef float v4f __attribute__((ext_vector_type(4)));

#define Wh   1024
#define HWh  (1024 * 512)
#define Wlr  512
#define HWlr (512 * 256)

#define THREADS 768
#define WAVES   12
#define NBLK    256
#define SLOTS   64        // 64 x 32 px = 2048 px per block; waves 0-3: 6 slots, 4-11: 5

// Activation buffer: fragment-major B-operand layout, in-place, wave-private.
// element (px, ch): half = px>>4, frag = ch>>5, lane' = ((ch>>3)&3)*16 + (px&15), off = ch&7
#define HALF_STRIDE 2052               // 4 frags * 512 + 4 pad (shorts)
#define ACT_SHORTS  (2 * HALF_STRIDE)  // 4104 shorts = 8208 B per wave
#define WF_N         53                // W0:32 frags, W1:16, W2:4, W3:1
#define WFRAG_SHORTS (WF_N * 512)
#define LDS_BYTES   ((WFRAG_SHORTS + WAVES * ACT_SHORTS) * 2)  // 54272 + 98496 = 152768

__device__ __forceinline__ unsigned short f2bf(float f) {
    union { float f; unsigned u; } v; v.f = f;
    unsigned r = v.u + 0x7FFFu + ((v.u >> 16) & 1u);  // RNE (cold paths only)
    return (unsigned short)(r >> 16);
}
// hot-path pack: round-half-up bias + v_perm grabbing the two high halves (3 VALU)
__device__ __forceinline__ unsigned pk2(float a, float b) {
    union { float f; unsigned u; } ua, ub;
    ua.f = a; ub.f = b;
    return __builtin_amdgcn_perm(ub.u + 0x8000u, ua.u + 0x8000u, 0x07060302u);
}
__device__ __forceinline__ float leaky(float x) { return fmaxf(x, 0.01f * x); }

// epilogue write: channels c0..c0+3 (c0 = 16*mt + 4*q) of pixel p, half h
__device__ __forceinline__ void ep_write(unsigned short* buf, int h, int c0, int p, uint2 v) {
    *(uint2*)(buf + h * HALF_STRIDE + (c0 >> 5) * 512 +
              (((c0 >> 3) & 3) * 16 + p) * 8 + (c0 & 7)) = v;
}

// staging loads for one 32-px slot: lane (p,q) fetches ch 8q..8q+7 of hr/lr
// at px=p (h0/l0) and px=p+16 (h1/l1)
__device__ __forceinline__ void ld32(const float* __restrict__ hr, const float* __restrict__ lr,
                                     int gbase, int p, int q,
                                     float (&h0)[8], float (&h1)[8],
                                     float (&l0)[8], float (&l1)[8]) {
    const int y  = gbase >> 10;
    const int x0 = gbase & 1023;
    const float* hb = hr + (size_t)y * Wh + x0 + p;
    const float* lb = lr + (size_t)(y >> 1) * Wlr + (x0 >> 1) + (p >> 1);
#pragma unroll
    for (int j = 0; j < 8; ++j) {
        const size_t hc = (size_t)(8 * q + j) * HWh;
        const size_t lc = (size_t)(8 * q + j) * HWlr;
        h0[j] = hb[hc];
        h1[j] = hb[hc + 16];
        l0[j] = lb[lc];
        l1[j] = lb[lc + 8];
    }
}

__global__ __launch_bounds__(THREADS, 3)
void cmfsm_kernel(const float* __restrict__ lr, const float* __restrict__ hr,
                  const float* __restrict__ w0g, const float* __restrict__ w1g,
                  const float* __restrict__ w2g, const float* __restrict__ w3g,
                  const float* __restrict__ w4g, const float* __restrict__ w5g,
                  const float* __restrict__ t0g, const float* __restrict__ t1g,
                  const float* __restrict__ t2g, const float* __restrict__ fwg,
                  float* __restrict__ out)
{
    extern __shared__ unsigned short smem[];
    unsigned short* wfrag = smem;                    // 53 lane-contiguous A-fragments
    unsigned short* actS  = smem + WFRAG_SHORTS;

    const int tid  = threadIdx.x;
    const int lane = tid & 63;
    const int wv   = tid >> 6;
    const int p    = lane & 15;   // MFMA n within a 16-px tile
    const int q    = lane >> 4;   // MFMA k-quad

    // ---- stage weights as A-fragments (W0 0..31, W1 32..47, W2 48..51, W3 52) ----
    for (int e = tid; e < 32 * 64; e += THREADS) {
        int f = e >> 6, l = e & 63;
        int mt = f >> 2, ks = f & 3, pp = l & 15, qq = l >> 4;
        const float* src = w0g + (mt * 16 + pp) * 128 + ks * 32 + qq * 8;
        unsigned short* dst = wfrag + f * 512 + l * 8;
#pragma unroll
        for (int j = 0; j < 8; ++j) dst[j] = f2bf(src[j]);
    }
    for (int e = tid; e < 16 * 64; e += THREADS) {
        int f = e >> 6, l = e & 63;
        int mt = f >> 2, ks = f & 3, pp = l & 15, qq = l >> 4;
        const float* src = w1g + (mt * 16 + pp) * 128 + ks * 32 + qq * 8;
        unsigned short* dst = wfrag + (32 + f) * 512 + l * 8;
#pragma unroll
        for (int j = 0; j < 8; ++j) dst[j] = f2bf(src[j]);
    }
    if (tid < 4 * 64) {
        int f = tid >> 6, l = tid & 63;
        int mt = f >> 1, ks = f & 1, pp = l & 15, qq = l >> 4;
        const float* src = w2g + (mt * 16 + pp) * 64 + ks * 32 + qq * 8;
        unsigned short* dst = wfrag + (48 + f) * 512 + l * 8;
#pragma unroll
        for (int j = 0; j < 8; ++j) dst[j] = f2bf(src[j]);
    }
    if (tid < 64) {
        int l = tid, pp = l & 15, qq = l >> 4;
        const float* src = w3g + pp * 32 + qq * 8;
        unsigned short* dst = wfrag + 52 * 512 + l * 8;
#pragma unroll
        for (int j = 0; j < 8; ++j) dst[j] = f2bf(src[j]);
    }

    // ---- fused layers 4+5: w45[r] = sum_j w5[j]*w4[j][4q+r] ----
    float w45[4];
#pragma unroll
    for (int r = 0; r < 4; ++r) {
        float s = 0.f;
#pragma unroll
        for (int j = 0; j < 8; ++j) s += w5g[j] * w4g[j * 16 + q * 4 + r];
        w45[r] = s;
    }

    // ---- weights2: 4 parity values ----
    float w2tab[4];
#pragma unroll
    for (int yp = 0; yp < 2; ++yp)
#pragma unroll
        for (int xp = 0; xp < 2; ++xp) {
            float i0 = xp ? 1.f : -1.f;
            float i1 = yp ? 1.f : -1.f;
            float i2 = 1.41421356237309505f;
            float h0[3], h1[2];
            for (int o = 0; o < 3; ++o)
                h0[o] = leaky(t0g[o*3+0]*i0 + t0g[o*3+1]*i1 + t0g[o*3+2]*i2);
            for (int o = 0; o < 2; ++o)
                h1[o] = leaky(t1g[o*3+0]*h0[0] + t1g[o*3+1]*h0[1] + t1g[o*3+2]*h0[2]);
            w2tab[yp*2+xp] = t2g[0]*h1[0] + t2g[1]*h1[1];
        }
    const float fa = fabsf(fwg[0]);
    const float fb = fabsf(fwg[1]);

    __syncthreads();   // wfrag ready; act buffers wave-private hereafter

    unsigned short* B = actS + wv * ACT_SHORTS;
    const v4f z4 = (v4f){0.f, 0.f, 0.f, 0.f};

    // ---- prefetch first slot's staging values into registers ----
    float xh0[8], xh1[8], xl0[8], xl1[8];
    ld32(hr, lr, (blockIdx.x * SLOTS + wv) * 32, p, q, xh0, xh1, xl0, xl1);

#pragma unroll 1
    for (int s = wv; s < SLOTS; s += WAVES) {
        const int gbase = (blockIdx.x * SLOTS + s) * 32;
        const int y     = gbase >> 10;

        // ---- build rep B-fragments directly in registers (both halves) ----
        v8s bfr[2][4];
#pragma unroll
        for (int hf = 0; hf < 2; ++hf) {
            const float* hv = hf ? xh1 : xh0;
            const float* lv = hf ? xl1 : xl0;
            unsigned* b0 = (unsigned*)&bfr[hf][0];
            unsigned* b1 = (unsigned*)&bfr[hf][1];
            unsigned* b2 = (unsigned*)&bfr[hf][2];
            unsigned* b3 = (unsigned*)&bfr[hf][3];
#pragma unroll
            for (int jj = 0; jj < 4; ++jj) {
                float l0 = lv[2*jj], l1 = lv[2*jj+1];
                float h0 = hv[2*jj], h1 = hv[2*jj+1];
                b0[jj] = pk2(l0, l1);                 // lr_up
                b1[jj] = pk2(h0, h1);                 // hr
                b2[jj] = pk2(l0 * h0, l1 * h1);       // product
                float d0 = l0 - h0, d1 = l1 - h1;
                b3[jj] = pk2(d0 * d0, d1 * d1);       // squared diff
            }
        }

        // ---- issue next slot's staging loads (overlap with the 4 layers) ----
        {
            const int ns = (s + WAVES < SLOTS) ? s + WAVES : s;
            ld32(hr, lr, (blockIdx.x * SLOTS + ns) * 32, p, q, xh0, xh1, xl0, xl1);
        }

        // ---- layer 0: 128 -> 128, B from regs, two mt-halves, out -> LDS act ----
#pragma unroll
        for (int mh = 0; mh < 2; ++mh) {
            v4f acc[4][2];
#pragma unroll
            for (int ks = 0; ks < 4; ++ks)
#pragma unroll
                for (int mi = 0; mi < 4; ++mi) {
                    v8s a = *(const v8s*)(wfrag + ((mh * 4 + mi) * 4 + ks) * 512 + lane * 8);
                    acc[mi][0] = __builtin_amdgcn_mfma_f32_16x16x32_bf16(
                        a, bfr[0][ks], ks == 0 ? z4 : acc[mi][0], 0, 0, 0);
                    acc[mi][1] = __builtin_amdgcn_mfma_f32_16x16x32_bf16(
                        a, bfr[1][ks], ks == 0 ? z4 : acc[mi][1], 0, 0, 0);
                }
#pragma unroll
            for (int mi = 0; mi < 4; ++mi) {
                const int c0 = 16 * (mh * 4 + mi) + 4 * q;
#pragma unroll
                for (int h = 0; h < 2; ++h) {
                    uint2 v;
                    v.x = pk2(leaky(acc[mi][h][0]), leaky(acc[mi][h][1]));
                    v.y = pk2(leaky(acc[mi][h][2]), leaky(acc[mi][h][3]));
                    ep_write(B, h, c0, p, v);
                }
            }
        }

        // ---- layer 1: 128 -> 64 (b-frags cached in regs -> in-place safe) ----
        {
            v8s bf[4][2];
#pragma unroll
            for (int ks = 0; ks < 4; ++ks) {
                bf[ks][0] = *(const v8s*)(B + ks * 512 + lane * 8);
                bf[ks][1] = *(const v8s*)(B + HALF_STRIDE + ks * 512 + lane * 8);
            }
            v4f acc[4][2];
#pragma unroll
            for (int ks = 0; ks < 4; ++ks)
#pragma unroll
                for (int mt = 0; mt < 4; ++mt) {
                    v8s a = *(const v8s*)(wfrag + (32 + mt * 4 + ks) * 512 + lane * 8);
                    acc[mt][0] = __builtin_amdgcn_mfma_f32_16x16x32_bf16(
                        a, bf[ks][0], ks == 0 ? z4 : acc[mt][0], 0, 0, 0);
                    acc[mt][1] = __builtin_amdgcn_mfma_f32_16x16x32_bf16(
                        a, bf[ks][1], ks == 0 ? z4 : acc[mt][1], 0, 0, 0);
                }
#pragma unroll
            for (int mt = 0; mt < 4; ++mt) {
                const int c0 = 16 * mt + 4 * q;
#pragma unroll
                for (int h = 0; h < 2; ++h) {
                    uint2 v;
                    v.x = pk2(leaky(acc[mt][h][0]), leaky(acc[mt][h][1]));
                    v.y = pk2(leaky(acc[mt][h][2]), leaky(acc[mt][h][3]));
                    ep_write(B, h, c0, p, v);
                }
            }
        }

        // ---- layer 2: 64 -> 32 ----
        {
            v8s bf[2][2];
#pragma unroll
            for (int ks = 0; ks < 2; ++ks) {
                bf[ks][0] = *(const v8s*)(B + ks * 512 + lane * 8);
                bf[ks][1] = *(const v8s*)(B + HALF_STRIDE + ks * 512 + lane * 8);
            }
            v4f acc[2][2];
#pragma unroll
            for (int ks = 0; ks < 2; ++ks)
#pragma unroll
                for (int mt = 0; mt < 2; ++mt) {
                    v8s a = *(const v8s*)(wfrag + (48 + mt * 2 + ks) * 512 + lane * 8);
                    acc[mt][0] = __builtin_amdgcn_mfma_f32_16x16x32_bf16(
                        a, bf[ks][0], ks == 0 ? z4 : acc[mt][0], 0, 0, 0);
                    acc[mt][1] = __builtin_amdgcn_mfma_f32_16x16x32_bf16(
                        a, bf[ks][1], ks == 0 ? z4 : acc[mt][1], 0, 0, 0);
                }
#pragma unroll
            for (int mt = 0; mt < 2; ++mt) {
                const int c0 = 16 * mt + 4 * q;
#pragma unroll
                for (int h = 0; h < 2; ++h) {
                    uint2 v;
                    v.x = pk2(leaky(acc[mt][h][0]), leaky(acc[mt][h][1]));
                    v.y = pk2(leaky(acc[mt][h][2]), leaky(acc[mt][h][3]));
                    ep_write(B, h, c0, p, v);
                }
            }
        }

        // ---- layer 3: 32 -> 16, fused 16->8->1, fuse with weights2 ----
        {
            v8s a = *(const v8s*)(wfrag + 52 * 512 + lane * 8);
            float res[2];
#pragma unroll
            for (int h = 0; h < 2; ++h) {
                v8s b = *(const v8s*)(B + h * HALF_STRIDE + lane * 8);
                v4f acc3 = __builtin_amdgcn_mfma_f32_16x16x32_bf16(a, b, z4, 0, 0, 0);
                float part = 0.f;
#pragma unroll
                for (int r = 0; r < 4; ++r) part += w45[r] * leaky(acc3[r]);
                part += __shfl_xor(part, 16, 64);
                part += __shfl_xor(part, 32, 64);
                res[h] = part;
            }
            const float wb = fb * w2tab[((y & 1) << 1) | (p & 1)];
            if (q == 0)      out[gbase + p]      = fa * res[0] + wb;
            else if (q == 1) out[gbase + 16 + p] = fa * res[1] + wb;
        }
    }
}

extern "C" void kernel_launch(void* const* d_in, const int* in_sizes, int n_in,
                              void* d_out, int out_size, void* d_ws, size_t ws_size,
                              hipStream_t stream) {
    const float* lr  = (const float*)d_in[0];
    const float* hr  = (const float*)d_in[1];
    const float* w0g = (const float*)d_in[2];
    const float* w1g = (const float*)d_in[3];
    const float* w2g = (const float*)d_in[4];
    const float* w3g = (const float*)d_in[5];
    const float* w4g = (const float*)d_in[6];
    const float* w5g = (const float*)d_in[7];
    const float* t0g = (const float*)d_in[8];
    const float* t1g = (const float*)d_in[9];
    const float* t2g = (const float*)d_in[10];
    const float* fwg = (const float*)d_in[11];
    float* out = (float*)d_out;

    hipLaunchKernelGGL(cmfsm_kernel, dim3(NBLK), dim3(THREADS), LDS_BYTES, stream,
                       lr, hr, w0g, w1g, w2g, w3g, w4g, w5g, t0g, t1g, t2g, fwg, out);
}